// Round 4
// baseline (439.494 us; speedup 1.0000x reference)
//
#include <hip/hip_runtime.h>
#include <hip/hip_bf16.h>

typedef unsigned short u16;
typedef __attribute__((ext_vector_type(8))) short short8v;
typedef __attribute__((ext_vector_type(4))) float f32x4;

typedef __attribute__((address_space(3))) char lds_char;
typedef const __attribute__((address_space(1))) char g_char;

__device__ __forceinline__ u16 f2bf(float f) {
    union { float f; unsigned int u; } x; x.f = f;
    unsigned int u = x.u;
    return (u16)((u + 0x7FFFu + ((u >> 16) & 1u)) >> 16);
}
__device__ __forceinline__ float bf2f(u16 h) {
    union { unsigned int u; float f; } x; x.u = ((unsigned int)h) << 16;
    return x.f;
}
__device__ __forceinline__ void gload16(const void* g, void* l) {
    __builtin_amdgcn_global_load_lds((g_char*)g, (lds_char*)l, 16, 0, 0);
}
template<int N> __device__ __forceinline__ void vm_wait() {
    asm volatile("s_waitcnt vmcnt(%0)" :: "i"(N) : "memory");
}
__device__ __forceinline__ void lgkm_barrier() {
    __builtin_amdgcn_sched_barrier(0);
    asm volatile("s_waitcnt lgkmcnt(0)" ::: "memory");
    __builtin_amdgcn_s_barrier();
    __builtin_amdgcn_sched_barrier(0);
}

// ---------------------------------------------------------------------------
// 128x128 bf16 MFMA GEMM, BK=64. 256 thr = 4 waves (2x2), wave tile 64x64
// (4x4 frags of 16x16x32). LDS all-bf16: Abuf[2]@{0,16K}, Bbuf[3]@{32K+i*16K}
// = 80 KB. A is reg-staged (global->VGPR->(cvt)->swizzled ds_write); B via
// global_load_lds with pre-swizzled source. Single barrier per K-step,
// counted vmcnt (loads stay in flight across barriers).
// Pipeline invariant at top of iter kt: outstanding = {B(kt+1), A(kt+1)}.
//   s1: issue B(kt+2)->Bbuf[(kt+2)%3], A(kt+2)->regset[kt&1]
//   s2: vmcnt(LPS)  -> forces B(kt+1) (LDS) and A(kt+1) (regs)
//   s3: ds_write A(kt+1)->Abuf[(kt+1)&1]   (wave-private regs, no barrier)
//   s4: compute(Abuf[kt&1], Bbuf[kt%3])    (guarded by PREVIOUS barrier)
//   s5: lgkmcnt(0); s_barrier
// EPI: 0=store bf16, 1=*V store bf16, 2=+bias,gelu store bf16, 3=+bias f32.
// AF32: A operand fp32, converted to bf16 between global load and ds_write.
// Requires K % 128 == 0 (nsteps even, >= 4).
// ---------------------------------------------------------------------------
template<int EPI, bool AF32>
__global__ __launch_bounds__(256, 2) void gemm_k(
    const void* __restrict__ Ap, int lda,
    const u16* __restrict__ Bt, int ldb,
    void* __restrict__ Cp, int ldc, int K,
    const float* __restrict__ bias,
    const u16* __restrict__ vmul, int ldv)
{
    __shared__ alignas(16) char smem[81920];
    constexpr int AR  = AF32 ? 8 : 4;     // uint4 regs per A stage
    constexpr int LPS = AF32 ? 12 : 8;    // vmem ops per stage pair (B + A)

    const int t    = threadIdx.x;
    const int lane = t & 63;
    const int wid  = t >> 6;
    const int m0   = blockIdx.x * 128;
    const int n0   = blockIdx.y * 128;
    const int wr   = wid >> 1, wc = wid & 1;
    const int lr   = lane & 15, q4 = lane >> 4;

    f32x4 acc[4][4];
    #pragma unroll
    for (int i = 0; i < 4; ++i)
        #pragma unroll
        for (int j = 0; j < 4; ++j)
            acc[i][j] = (f32x4){0.f, 0.f, 0.f, 0.f};

    uint4 rA0[AR], rA1[AR];
    const int nsteps = K >> 6;

    // ---- issue A global loads for tile kt into reg set r ----
    auto loadA = [&](uint4* r, int kt) {
        const int k0 = kt << 6;
        if constexpr (AF32) {
            const float* A32 = (const float*)Ap;
            #pragma unroll
            for (int p = 0; p < 8; ++p) {
                int row = wid * 32 + p * 4 + (lane >> 4);
                r[p] = *(const uint4*)(A32 + (size_t)(m0 + row) * (size_t)lda
                                       + k0 + (lane & 15) * 4);
            }
        } else {
            const u16* A16 = (const u16*)Ap;
            #pragma unroll
            for (int p = 0; p < 4; ++p) {
                int row = wid * 32 + p * 8 + (lane >> 3);
                r[p] = *(const uint4*)(A16 + (size_t)(m0 + row) * (size_t)lda
                                       + k0 + (lane & 7) * 8);
            }
        }
    };
    // ---- issue B global_load_lds for tile kt into Bbuf at byte off boff ----
    auto stageB = [&](int boff, int kt) {
        const int k0 = kt << 6;
        #pragma unroll
        for (int p = 0; p < 4; ++p) {
            int o   = p * 4096 + t * 16;
            int row = o >> 7;
            int cb  = (o & 127) ^ ((row & 7) << 4);   // inverse swizzle on src
            gload16(Bt + (size_t)(n0 + row) * (size_t)ldb + k0 + (cb >> 1),
                    smem + 32768 + boff + o);
        }
    };
    // ---- convert (if AF32) + swizzled ds_write of reg set r into Abuf ----
    auto writeA = [&](const uint4* r, int aoff) {
        char* base = smem + aoff;
        if constexpr (AF32) {
            #pragma unroll
            for (int p = 0; p < 8; ++p) {
                int row = wid * 32 + p * 4 + (lane >> 4);
                int gq  = lane & 15;
                const float* f = (const float*)&r[p];
                uint2 w;
                w.x = (unsigned)f2bf(f[0]) | ((unsigned)f2bf(f[1]) << 16);
                w.y = (unsigned)f2bf(f[2]) | ((unsigned)f2bf(f[3]) << 16);
                int sw = (((gq >> 1) * 16) ^ ((row & 7) << 4)) | ((gq & 1) * 8);
                *(uint2*)(base + row * 128 + sw) = w;
            }
        } else {
            #pragma unroll
            for (int p = 0; p < 4; ++p) {
                int row = wid * 32 + p * 8 + (lane >> 3);
                int gq  = lane & 7;
                int sw = (gq * 16) ^ ((row & 7) << 4);
                *(uint4*)(base + row * 128 + sw) = r[p];
            }
        }
    };
    // ---- one K-step of MFMAs from Abuf(aoff), Bbuf(boff rel) ----
    auto compute = [&](int aoff, int boff) {
        const char* Ab = smem + aoff;
        const char* Bb = smem + 32768 + boff;
        #pragma unroll
        for (int kh = 0; kh < 2; ++kh) {
            short8v a[4], b[4];
            #pragma unroll
            for (int i = 0; i < 4; ++i) {
                int ar = wr * 64 + i * 16 + lr;
                a[i] = *(const short8v*)(Ab + ar * 128 +
                        ((kh * 64 + q4 * 16) ^ ((ar & 7) << 4)));
            }
            #pragma unroll
            for (int i = 0; i < 4; ++i) {
                int br = wc * 64 + i * 16 + lr;
                b[i] = *(const short8v*)(Bb + br * 128 +
                        ((kh * 64 + q4 * 16) ^ ((br & 7) << 4)));
            }
            #pragma unroll
            for (int mi = 0; mi < 4; ++mi)
                #pragma unroll
                for (int ni = 0; ni < 4; ++ni)
                    acc[mi][ni] = __builtin_amdgcn_mfma_f32_16x16x32_bf16(
                        a[mi], b[ni], acc[mi][ni], 0, 0, 0);
        }
    };
    auto rot = [](int x) { return x == 32768 ? 0 : x + 16384; };

    // ---- prologue: stage tiles 0,1; commit A(0) ----
    stageB(0, 0);      loadA(rA0, 0);
    stageB(16384, 1);  loadA(rA1, 1);
    vm_wait<LPS>();            // forces B(0)+A(0); leaves {B(1),A(1)}
    writeA(rA0, 0);
    lgkm_barrier();

    int brd = 0;       // Bbuf rel offset for compute(kt)
    int bwr = 32768;   // Bbuf rel offset for stage of kt+2

    // ---- main loop, unrolled x2 for static reg-set parity ----
    for (int kt = 0; kt < nsteps - 3; kt += 2) {
        // even iter: issue -> rA0, commit rA1 (A(kt+1)) -> Abuf1
        stageB(bwr, kt + 2); loadA(rA0, kt + 2);
        vm_wait<LPS>();
        writeA(rA1, 16384);
        compute(0, brd);
        lgkm_barrier();
        brd = rot(brd); bwr = rot(bwr);
        // odd iter: issue -> rA1, commit rA0 -> Abuf0
        stageB(bwr, kt + 3); loadA(rA1, kt + 3);
        vm_wait<LPS>();
        writeA(rA0, 0);
        compute(16384, brd);
        lgkm_barrier();
        brd = rot(brd); bwr = rot(bwr);
    }
    // ---- tails: kt = nsteps-2 (even), nsteps-1 (odd) ----
    vm_wait<0>();
    writeA(rA1, 16384);        // A(nsteps-1), issued in last odd iter
    compute(0, brd);
    lgkm_barrier();
    brd = rot(brd);
    compute(16384, brd);

    // ---- epilogue ----
    #pragma unroll
    for (int mi = 0; mi < 4; ++mi) {
        #pragma unroll
        for (int ni = 0; ni < 4; ++ni) {
            const int gc = n0 + wc * 64 + ni * 16 + lr;
            #pragma unroll
            for (int j = 0; j < 4; ++j) {
                const int gr = m0 + wr * 64 + mi * 16 + q4 * 4 + j;
                float v = acc[mi][ni][j];
                if constexpr (EPI == 0) {
                    ((u16*)Cp)[(size_t)gr * ldc + gc] = f2bf(v);
                } else if constexpr (EPI == 1) {
                    v *= bf2f(vmul[(size_t)gr * ldv + gc]);
                    ((u16*)Cp)[(size_t)gr * ldc + gc] = f2bf(v);
                } else if constexpr (EPI == 2) {
                    float x = v + bias[gc];
                    float g = 0.5f * x * (1.0f + erff(x * 0.70710678118f));
                    ((u16*)Cp)[(size_t)gr * ldc + gc] = f2bf(g);
                } else {
                    ((float*)Cp)[(size_t)gr * ldc + gc] = v + bias[gc];
                }
            }
        }
    }
}

// ---------------------------------------------------------------------------
// Convert Wq|Wk|Wv (concat) and W1 to bf16. (x_in now consumed fp32 directly.)
// ---------------------------------------------------------------------------
__global__ void k_convert(const float* __restrict__ Wq, const float* __restrict__ Wk,
                          const float* __restrict__ Wv, const float* __restrict__ W1,
                          u16* __restrict__ WqkvB, u16* __restrict__ W1B)
{
    const int C2 = 196608;   // Wqkv float4 chunks (3*512*512/4)
    const int C3 = 65536;    // W1 chunks
    for (int i = blockIdx.x * blockDim.x + threadIdx.x; i < C2 + C3;
         i += gridDim.x * blockDim.x) {
        const float* src; u16* dst;
        if (i < C2) {
            int e = i * 4;
            if (e < 262144)      src = Wq + e;
            else if (e < 524288) src = Wk + (e - 262144);
            else                 src = Wv + (e - 524288);
            dst = WqkvB + e;
        } else {
            int e = (i - C2) * 4;
            src = W1 + e; dst = W1B + e;
        }
        float4 v = *reinterpret_cast<const float4*>(src);
        ushort4 h;
        h.x = f2bf(v.x); h.y = f2bf(v.y); h.z = f2bf(v.z); h.w = f2bf(v.w);
        *reinterpret_cast<ushort4*>(dst) = h;
    }
}

// ---------------------------------------------------------------------------
// TXT[c][m] = bf16(task_x[m][c])  — 64x64 tiles through LDS.
// ---------------------------------------------------------------------------
__global__ void k_transpose(const float* __restrict__ tx, u16* __restrict__ txt)
{
    __shared__ float tile[64][65];
    const int n0 = blockIdx.x * 64;
    const int c0 = blockIdx.y * 64;
    const int t = threadIdx.x;
    #pragma unroll
    for (int p = 0; p < 4; ++p) {
        int q = p * 256 + t;
        int r = q >> 4, s = q & 15;
        float4 v = *reinterpret_cast<const float4*>(tx + (size_t)(n0 + r) * 512 + c0 + s * 4);
        tile[r][s * 4 + 0] = v.x; tile[r][s * 4 + 1] = v.y;
        tile[r][s * 4 + 2] = v.z; tile[r][s * 4 + 3] = v.w;
    }
    __syncthreads();
    #pragma unroll
    for (int p = 0; p < 4; ++p) {
        int q = p * 256 + t;
        int cc = q >> 4, s = q & 15;
        ushort4 h;
        h.x = f2bf(tile[s * 4 + 0][cc]); h.y = f2bf(tile[s * 4 + 1][cc]);
        h.z = f2bf(tile[s * 4 + 2][cc]); h.w = f2bf(tile[s * 4 + 3][cc]);
        *reinterpret_cast<ushort4*>(txt + (size_t)(c0 + cc) * 8192 + n0 + s * 4) = h;
    }
}

// ---------------------------------------------------------------------------
// colsq[j] = sum_n QKV[n,j]^2, j in [0,1024)
// ---------------------------------------------------------------------------
__global__ void k_colsq(const u16* __restrict__ QKV, float* __restrict__ colsq)
{
    const int t = threadIdx.x;
    const int c8 = t & 127, rs = t >> 7;
    float a[8];
    #pragma unroll
    for (int j = 0; j < 8; ++j) a[j] = 0.f;
    const int row0 = blockIdx.x * 64;
    for (int rr = rs; rr < 64; rr += 2) {
        uint4 u = *reinterpret_cast<const uint4*>(QKV + (size_t)(row0 + rr) * 1536 + c8 * 8);
        unsigned int w[4] = {u.x, u.y, u.z, u.w};
        #pragma unroll
        for (int q = 0; q < 4; ++q) {
            float f0 = bf2f((u16)(w[q] & 0xffffu));
            float f1 = bf2f((u16)(w[q] >> 16));
            a[2 * q]     += f0 * f0;
            a[2 * q + 1] += f1 * f1;
        }
    }
    #pragma unroll
    for (int j = 0; j < 8; ++j) atomicAdd(&colsq[c8 * 8 + j], a[j]);
}

// ---------------------------------------------------------------------------
// Per-head Gram partials: S[h,d,e] += sum_{n in chunk} K[n,h64+d]*Q[n,h64+e]
// ---------------------------------------------------------------------------
__global__ void k_gram(const u16* __restrict__ QKV, float* __restrict__ Sb)
{
    __shared__ u16 Qt[4][64];
    __shared__ u16 Kt[4][64];
    const int h = blockIdx.x >> 6;
    const int chunk = blockIdx.x & 63;
    const int t = threadIdx.x;
    const int e = t & 63;
    const int dg = t >> 6;
    float acc[16];
    #pragma unroll
    for (int k = 0; k < 16; ++k) acc[k] = 0.f;
    const int rowbase = chunk * 128;
    for (int p = 0; p < 32; ++p) {
        __syncthreads();
        if (t < 64) {
            const int mat = t >> 5, sub = t & 31, r = sub >> 3, seg = sub & 7;
            const int row = rowbase + p * 4 + r;
            const int col = (mat ? 512 : 0) + h * 64 + seg * 8;
            uint4 v = *reinterpret_cast<const uint4*>(QKV + (size_t)row * 1536 + col);
            u16* dst = mat ? &Kt[r][seg * 8] : &Qt[r][seg * 8];
            *reinterpret_cast<uint4*>(dst) = v;
        }
        __syncthreads();
        #pragma unroll
        for (int r = 0; r < 4; ++r) {
            const float q = bf2f(Qt[r][e]);
            short8v kv0 = *reinterpret_cast<const short8v*>(&Kt[r][dg * 16]);
            short8v kv1 = *reinterpret_cast<const short8v*>(&Kt[r][dg * 16 + 8]);
            #pragma unroll
            for (int k = 0; k < 8; ++k) {
                acc[k]     += bf2f((u16)kv0[k]) * q;
                acc[k + 8] += bf2f((u16)kv1[k]) * q;
            }
        }
    }
    #pragma unroll
    for (int k = 0; k < 16; ++k)
        atomicAdd(&Sb[h * 4096 + (dg * 16 + k) * 64 + e], acc[k]);
}

// ---------------------------------------------------------------------------
// attn[h,d,e] = softmax_e( S/(||k_d|| ||q_e||) * rescale[h] )
// ---------------------------------------------------------------------------
__global__ void k_softmax(const float* __restrict__ Sb, const float* __restrict__ colsq,
                          const float* __restrict__ rescale, float* __restrict__ Abuf)
{
    const int h = blockIdx.x;
    const int t = threadIdx.x;   // 64
    const float rsc = rescale[h];
    const float nq = fmaxf(sqrtf(colsq[h * 64 + t]), 1e-12f);
    for (int d = 0; d < 64; ++d) {
        const float nk = fmaxf(sqrtf(colsq[512 + h * 64 + d]), 1e-12f);
        float v = Sb[h * 4096 + d * 64 + t] / (nk * nq) * rsc;
        float m = v;
        #pragma unroll
        for (int off = 32; off > 0; off >>= 1) m = fmaxf(m, __shfl_xor(m, off, 64));
        float p = expf(v - m);
        float s = p;
        #pragma unroll
        for (int off = 32; off > 0; off >>= 1) s += __shfl_xor(s, off, 64);
        Abuf[h * 4096 + d * 64 + t] = p / s;
    }
}

// ---------------------------------------------------------------------------
// BtC[j][c]: c<512 -> fold attn with Wp; c>=512 -> W2. bsum[j] = bp[j]+b2[j].
// ---------------------------------------------------------------------------
__global__ void k_buildbt(const float* __restrict__ Abuf, const float* __restrict__ Wp,
                          const float* __restrict__ W2, const float* __restrict__ bp,
                          const float* __restrict__ b2, u16* __restrict__ BtC,
                          float* __restrict__ bsum)
{
    const int g = blockIdx.x * 256 + threadIdx.x;
    const int j = g >> 10, c = g & 1023;
    if (c < 512) {
        const int h = c >> 6, e = c & 63;
        const float* Ah = Abuf + h * 4096 + e;
        const float* Wph = Wp + (size_t)j * 512 + h * 64;
        float s = 0.f;
        #pragma unroll 8
        for (int d = 0; d < 64; ++d) s += Ah[d * 64] * Wph[d];
        BtC[(size_t)j * 1024 + c] = f2bf(s);
        if (c == 0) bsum[j] = bp[j] + b2[j];
    } else {
        BtC[(size_t)j * 1024 + c] = f2bf(W2[(size_t)j * 512 + (c - 512)]);
    }
}

// ---------------------------------------------------------------------------
extern "C" void kernel_launch(void* const* d_in, const int* in_sizes, int n_in,
                              void* d_out, int out_size, void* d_ws, size_t ws_size,
                              hipStream_t stream)
{
    const float* x_in    = (const float*)d_in[0];
    const float* task_x  = (const float*)d_in[1];
    const float* Ges     = (const float*)d_in[2];
    const float* Wq      = (const float*)d_in[3];
    const float* Wk      = (const float*)d_in[4];
    const float* Wv      = (const float*)d_in[5];
    const float* rescale = (const float*)d_in[6];
    const float* Wp      = (const float*)d_in[7];
    const float* bp      = (const float*)d_in[8];
    const float* W1      = (const float*)d_in[9];
    const float* b1      = (const float*)d_in[10];
    const float* W2      = (const float*)d_in[11];
    const float* b2      = (const float*)d_in[12];
    float* out = (float*)d_out;
    char* ws = (char*)d_ws;

    u16*   TXT   = (u16*)  (ws + 8388608);      //  512x8192  bf16
    u16*   QKV   = (u16*)  (ws + 16777216);     //  8192x1536 bf16
    u16*   AH    = (u16*)  (ws + 41943040);     //  8192x1024 bf16
    u16*   WqkvB = (u16*)  (ws + 58720256);     //  1536x512  bf16
    u16*   W1B   = (u16*)  (ws + 60293120);     //  512x512   bf16
    u16*   BtC   = (u16*)  (ws + 60817408);     //  512x1024  bf16
    float* colsq = (float*)(ws + 61865984);     //  1024 f32
    float* Sb    = (float*)(ws + 61870080);     //  8x64x64 f32
    float* Abuf  = (float*)(ws + 62001152);     //  8x64x64 f32
    float* bsum  = (float*)(ws + 62132224);     //  512 f32
    (void)in_sizes; (void)n_in; (void)out_size; (void)ws_size;

    hipMemsetAsync(colsq, 0, 4096 + 131072, stream);

    k_convert  <<<1024, 256, 0, stream>>>(Wq, Wk, Wv, W1, WqkvB, W1B);
    k_transpose<<<dim3(128, 8), 256, 0, stream>>>(task_x, TXT);

    // QKV = x @ [Wq;Wk;Wv]^T   (M=8192, N=1536, K=512; A = x_in fp32)
    gemm_k<0, true><<<dim3(64, 12), 256, 0, stream>>>(
        x_in, 512, WqkvB, 512, QKV, 1536, 512, nullptr, nullptr, 0);

    k_colsq  <<<128, 256, 0, stream>>>(QKV, colsq);
    k_gram   <<<512, 256, 0, stream>>>(QKV, Sb);
    k_softmax<<<8, 64, 0, stream>>>(Sb, colsq, rescale, Abuf);
    k_buildbt<<<2048, 256, 0, stream>>>(Abuf, Wp, W2, bp, b2, BtC, bsum);

    // guided = (Ges @ task_x) * V   (M=8192, N=512, K=8192; A fp32)
    gemm_k<1, true><<<dim3(64, 4), 256, 0, stream>>>(
        Ges, 8192, TXT, 8192, AH, 1024, 8192, nullptr, QKV + 1024, 1536);

    // hidden = gelu(V @ W1^T + b1)  (M=8192, N=512, K=512)
    gemm_k<2, false><<<dim3(64, 4), 256, 0, stream>>>(
        QKV + 1024, 1536, W1B, 512, AH + 512, 1024, 512, b1, nullptr, 0);

    // out = [guided|hidden] @ BtC^T + (bp+b2)  (M=8192, N=512, K=1024)
    gemm_k<3, false><<<dim3(64, 4), 256, 0, stream>>>(
        AH, 1024, BtC, 1024, out, 512, 1024, bsum, nullptr, 0);
}